// Round 4
// baseline (637.405 us; speedup 1.0000x reference)
//
#include <hip/hip_runtime.h>
#include <hip/hip_bf16.h>
#include <math.h>

typedef __attribute__((ext_vector_type(4))) float f32x4;
typedef __attribute__((ext_vector_type(8))) short s16x8;
typedef __hip_bfloat16 bf16;

#define MB (1024ull*1024ull)
// workspace layout (bytes) — total 17 MB
#define GATE_OFF    (0ull)          // 1024*4 f32 = 16KB
#define ACTW_OFF    (16ull*1024)    // 9 f32
#define U_OFF       (20ull*1024)    // 2048 f32
#define CMEAN_OFF   (28ull*1024)    // 1024 f32
#define HIDDEN_OFF  (1ull*MB)       // bf16 1024x2048 (4MB)
#define RATT_OFF    (5ull*MB)       // bf16 1024x2048 (4MB) logits -> softmax in-place
#define CAND_OFF    (9ull*MB)       // bf16 1024x1024 (2MB)
#define PREDS_OFF   (11ull*MB)      // f32 1024x512  (2MB)
#define READ_OFF    (13ull*MB)      // f32 1024x1024 (4MB) -> ends 17MB

__device__ __forceinline__ short f2bf_s(float f) {
    bf16 h = __float2bfloat16(f);
    return *reinterpret_cast<short*>(&h);
}

__device__ __forceinline__ float qact(float x, const float* w) {
    float ex  = __expf(x);
    float sig = 1.f / (1.f + __expf(-x));
    float elu = x > 0.f ? x : ex - 1.f;
    float th  = tanhf(x);
    float rel = fmaxf(x, 0.f);
    float silu = x * sig;
    float gel = 0.5f * x * (1.f + erff(x * 0.70710678118654752f));
    float sel = 1.0507009873554805f * (x > 0.f ? x : 1.6732632423543772f * (ex - 1.f));
    float sp  = (x > 15.f) ? x : log1pf(ex);
    float mish = x * tanhf(sp);
    return w[0]*sig + w[1]*elu + w[2]*th + w[3]*rel + w[4]*silu
         + w[5]*gel + w[6]*sel + w[7]*mish + w[8]*x;
}

// ---------------- gate softmax + act-weight softmax (all f32) ----------------
__global__ __launch_bounds__(256) void k_gate(const float* __restrict__ x,
                                              const float* __restrict__ gw,
                                              const float* __restrict__ gb,
                                              const float* __restrict__ aw_in,
                                              float* __restrict__ gate,
                                              float* __restrict__ actw) {
    int b = blockIdx.x, t = threadIdx.x, w = t >> 6, lane = t & 63;
    __shared__ float l[4];
    float s = 0.f;
    for (int k = lane; k < 1024; k += 64)
        s += x[(size_t)b*1024 + k] * gw[k*4 + w];
    #pragma unroll
    for (int off = 32; off; off >>= 1) s += __shfl_xor(s, off);
    if (lane == 0) l[w] = s + gb[w];
    __syncthreads();
    if (t == 0) {
        float m = fmaxf(fmaxf(l[0], l[1]), fmaxf(l[2], l[3]));
        float e0 = __expf(l[0]-m), e1 = __expf(l[1]-m), e2 = __expf(l[2]-m), e3 = __expf(l[3]-m);
        float inv = 1.f / (e0+e1+e2+e3);
        gate[b*4+0] = e0*inv; gate[b*4+1] = e1*inv;
        gate[b*4+2] = e2*inv; gate[b*4+3] = e3*inv;
    }
    if (b == 0 && t == 64) {
        float a[9]; float m = -1e30f;
        for (int i = 0; i < 9; i++) { a[i] = aw_in[i]; m = fmaxf(m, a[i]); }
        float ss = 0.f;
        for (int i = 0; i < 9; i++) { a[i] = __expf(a[i]-m); ss += a[i]; }
        float inv = 1.f / ss;
        for (int i = 0; i < 9; i++) actw[i] = a[i]*inv;
    }
}

// ---------------- GEMM (NN): C(MxN) = A(MxK) @ B(KxN), 128x128 tile, BK=32 ----------------
// A: fp32 (AF32=1) or bf16 (AF32=0). B: always fp32, converted to bf16 during staging.
// B tile transposed into LDS with XOR k-group swizzle; fragment reads are ds_read_b128.
// MODE 0: outH = bf16(acc+bias)             [att logits]
// MODE 1: outH = bf16(tanh(acc+bias))       [cand]
// MODE 2: outF = acc+bias                   [preds]
// MODE 3: outF = acc                        [read]
// MODE 4: hidden epilogue (gate contraction over n, qact, mask) -> bf16
template <int MODE, int AF32>
__global__ __launch_bounds__(256, 2) void gemm_nn(
        const void* __restrict__ Av, const float* __restrict__ B,
        int K, int ldb,
        const float* __restrict__ bias,
        float* __restrict__ outF, bf16* __restrict__ outH,
        const float* __restrict__ gate, const float* __restrict__ actw,
        const float* __restrict__ mask, int outStride) {
    __shared__ __align__(16) short sA[128*32];   // A tile, row-major k-contiguous
    __shared__ __align__(16) short sB[128*32];   // B tile transposed: sB[n][k-swizzled]
    int t = threadIdx.x, lane = t & 63;
    int rowBase = blockIdx.y * 128, colBase = blockIdx.x * 128;
    int lm = lane & 15, lq = lane >> 4;
    int w = t >> 6;
    int qm = (w >> 1) * 64, qn = (w & 1) * 64;

    f32x4 acc[4][4];
    #pragma unroll
    for (int i = 0; i < 4; i++)
        #pragma unroll
        for (int j = 0; j < 4; j++) acc[i][j] = (f32x4){0.f, 0.f, 0.f, 0.f};

    // A staging map: row = t>>2 (and +64), kchunk = (t&3)*8
    int ar = t >> 2, ak = (t & 3) * 8;
    // B staging map: k = t>>3 (0..31), n-base = (t&7)*16 (16 consecutive cols)
    int bk = t >> 3, bn0 = (t & 7) * 16;
    int swz = (((t >> 6) ^ (t & 3)) << 3) | (bk & 7);  // ((kg ^ g(n)) << 3) | (k&7)

    for (int k0 = 0; k0 < K; k0 += 32) {
        __syncthreads();
        if (AF32) {
            const float* Af = (const float*)Av;
            #pragma unroll
            for (int h = 0; h < 2; h++) {
                int r = ar + h*64;
                const float* src = Af + (size_t)(rowBase + r)*K + k0 + ak;
                s16x8 av;
                #pragma unroll
                for (int j = 0; j < 8; j++) av[j] = f2bf_s(src[j]);
                *reinterpret_cast<s16x8*>(sA + r*32 + ak) = av;
            }
        } else {
            const bf16* Ab = (const bf16*)Av;
            *reinterpret_cast<s16x8*>(sA + ar*32 + ak) =
                *reinterpret_cast<const s16x8*>(Ab + (size_t)(rowBase + ar)*K + k0 + ak);
            *reinterpret_cast<s16x8*>(sA + (ar + 64)*32 + ak) =
                *reinterpret_cast<const s16x8*>(Ab + (size_t)(rowBase + ar + 64)*K + k0 + ak);
        }
        const float* bsrc = B + (size_t)(k0 + bk)*ldb + colBase + bn0;
        #pragma unroll
        for (int j = 0; j < 16; j++)
            sB[(bn0 + j)*32 + swz] = f2bf_s(bsrc[j]);
        __syncthreads();
        s16x8 af[4], bfr[4];
        #pragma unroll
        for (int mi = 0; mi < 4; mi++)
            af[mi] = *reinterpret_cast<const s16x8*>(sA + (qm + mi*16 + lm)*32 + lq*8);
        #pragma unroll
        for (int ni = 0; ni < 4; ni++) {
            int n = qn + ni*16 + lm;
            bfr[ni] = *reinterpret_cast<const s16x8*>(sB + n*32 + ((lq ^ ni) << 3));
        }
        #pragma unroll
        for (int mi = 0; mi < 4; mi++)
            #pragma unroll
            for (int ni = 0; ni < 4; ni++)
                acc[mi][ni] = __builtin_amdgcn_mfma_f32_16x16x32_bf16(af[mi], bfr[ni], acc[mi][ni], 0, 0, 0);
    }

    if (MODE == 4) {
        float aw[9];
        #pragma unroll
        for (int i = 0; i < 9; i++) aw[i] = actw[i];
        #pragma unroll
        for (int mi = 0; mi < 4; mi++) {
            int row0 = rowBase + qm + mi*16 + lq*4;
            #pragma unroll
            for (int ni = 0; ni < 4; ni++) {
                int col = colBase + qn + ni*16 + lm;     // flat un index
                int n = col & 3;
                float bb = bias[col];
                f32x4 v = acc[mi][ni];
                #pragma unroll
                for (int r = 0; r < 4; r++) v[r] = (v[r] + bb) * gate[(row0 + r)*4 + n];
                #pragma unroll
                for (int r = 0; r < 4; r++) v[r] += __shfl_xor(v[r], 1);
                #pragma unroll
                for (int r = 0; r < 4; r++) v[r] += __shfl_xor(v[r], 2);
                if ((lane & 3) == 0) {
                    int uu = col >> 2;
                    float mk = mask[uu];
                    #pragma unroll
                    for (int r = 0; r < 4; r++)
                        outH[(size_t)(row0 + r)*outStride + uu] = __float2bfloat16(qact(v[r], aw) * mk);
                }
            }
        }
    } else {
        #pragma unroll
        for (int mi = 0; mi < 4; mi++) {
            int row0 = rowBase + qm + mi*16 + lq*4;
            #pragma unroll
            for (int ni = 0; ni < 4; ni++) {
                int col = colBase + qn + ni*16 + lm;
                float bb = (MODE == 3) ? 0.f : bias[col];
                #pragma unroll
                for (int r = 0; r < 4; r++) {
                    float vv = acc[mi][ni][r] + bb;
                    size_t oi = (size_t)(row0 + r)*outStride + col;
                    if (MODE == 0) outH[oi] = __float2bfloat16(vv);
                    if (MODE == 1) outH[oi] = __float2bfloat16(tanhf(vv));
                    if (MODE == 2 || MODE == 3) outF[oi] = vv;
                }
            }
        }
    }
}

// ---------------- in-place row softmax over 2048 cols (bf16 buffer) ----------------
__global__ __launch_bounds__(256) void k_softmax(bf16* __restrict__ ratt) {
    int b = blockIdx.x, t = threadIdx.x, w = t >> 6, lane = t & 63;
    __shared__ float red[8];
    bf16* row = ratt + (size_t)b*2048;
    float v[8];
    float mx = -1e30f;
    #pragma unroll
    for (int j = 0; j < 8; j++) {
        v[j] = __bfloat162float(row[t + j*256]);
        mx = fmaxf(mx, v[j]);
    }
    #pragma unroll
    for (int off = 32; off; off >>= 1) mx = fmaxf(mx, __shfl_xor(mx, off));
    if (lane == 0) red[w] = mx;
    __syncthreads();
    mx = fmaxf(fmaxf(red[0], red[1]), fmaxf(red[2], red[3]));
    float s = 0.f;
    #pragma unroll
    for (int j = 0; j < 8; j++) { v[j] = __expf(v[j] - mx); s += v[j]; }
    #pragma unroll
    for (int off = 32; off; off >>= 1) s += __shfl_xor(s, off);
    if (lane == 0) red[4 + w] = s;
    __syncthreads();
    float inv = 1.f / (red[4] + red[5] + red[6] + red[7]);
    #pragma unroll
    for (int j = 0; j < 8; j++)
        row[t + j*256] = __float2bfloat16(v[j] * inv);
}

// ---------------- column means: u[m] (2048), cmean[d] (1024) ----------------
__global__ __launch_bounds__(256) void k_colmeans(const bf16* __restrict__ ratt,
                                                  const bf16* __restrict__ cand,
                                                  const float* __restrict__ update_gate,
                                                  float* __restrict__ u,
                                                  float* __restrict__ cmean) {
    int col = blockIdx.x*256 + threadIdx.x;       // 12 blocks -> 0..3071
    if (col < 2048) {
        float s = 0.f;
        for (int b = 0; b < 1024; b++) s += __bfloat162float(ratt[(size_t)b*2048 + col]);
        u[col] = (s * (1.f/1024.f)) * update_gate[col];
    } else {
        int d = col - 2048;
        float s = 0.f;
        for (int b = 0; b < 1024; b++) s += __bfloat162float(cand[(size_t)b*1024 + d]);
        cmean[d] = s * (1.f/1024.f);
    }
}

// ---------------- new_mem blend (f32 out) ----------------
__global__ __launch_bounds__(256) void k_newmem(const float* __restrict__ mem,
                                                const float* __restrict__ u,
                                                const float* __restrict__ cmean,
                                                float* __restrict__ out1) {
    int idx = blockIdx.x*256 + threadIdx.x;       // 2M
    int m = idx >> 10, d = idx & 1023;
    float um = u[m];
    out1[idx] = mem[idx] * (1.f - um) + um * cmean[d];
}

// ---------------- critic + final gating (f32) ----------------
__global__ __launch_bounds__(256) void k_critic(
        const float* __restrict__ readv, const float* __restrict__ preds,
        const bf16* __restrict__ hidden,
        const float* cw1, const float* cb1, const float* cw2, const float* cb2,
        const float* cw3, const float* cb3, const float* cw4, const float* cb4,
        const float* cw5, const float* cb5, const float* thr,
        float* __restrict__ out0) {
    __shared__ float feat[96];
    __shared__ float fused[64];
    __shared__ float gsh;
    int b = blockIdx.x, t = threadIdx.x;
    if (t < 96) {
        float s = 0.f, bias;
        if (t < 32) {
            for (int k = 0; k < 1024; k++) s += readv[(size_t)b*1024 + k] * cw1[k*32 + t];
            bias = cb1[t];
        } else if (t < 64) {
            int j = t - 32;
            for (int k = 0; k < 512; k++) s += preds[(size_t)b*512 + k] * cw2[k*32 + j];
            bias = cb2[j];
        } else {
            int j = t - 64;
            for (int k = 0; k < 2048; k++) s += __bfloat162float(hidden[(size_t)b*2048 + k]) * cw3[k*32 + j];
            bias = cb3[j];
        }
        feat[t] = fmaxf(s + bias, 0.f);
    }
    __syncthreads();
    if (t < 64) {
        float s = 0.f;
        for (int k = 0; k < 96; k++) s += feat[k] * cw4[k*64 + t];
        fused[t] = fmaxf(s + cb4[t], 0.f);
    }
    __syncthreads();
    if (t == 0) {
        float s = 0.f;
        for (int k = 0; k < 64; k++) s += fused[k] * cw5[k*2];
        s += cb5[0] - thr[0];
        gsh = 1.f / (1.f + __expf(-s));
    }
    __syncthreads();
    float g = gsh;
    for (int o = t; o < 512; o += 256)
        out0[(size_t)b*512 + o] = preds[(size_t)b*512 + o] * g;
}

extern "C" void kernel_launch(void* const* d_in, const int* in_sizes, int n_in,
                              void* d_out, int out_size, void* d_ws, size_t ws_size,
                              hipStream_t stream) {
    const float* x        = (const float*)d_in[0];
    const float* w_       = (const float*)d_in[1];   // (1024, 2048*4) row-major
    const float* b_bias   = (const float*)d_in[2];   // (2048*4)
    const float* gate_w   = (const float*)d_in[3];
    const float* gate_b   = (const float*)d_in[4];
    const float* act_w    = (const float*)d_in[5];
    const float* mask     = (const float*)d_in[6];
    const float* mem      = (const float*)d_in[7];   // (2048, 1024)
    const float* att_w    = (const float*)d_in[8];   // (2048, 2048)
    const float* att_b    = (const float*)d_in[9];
    const float* write_w  = (const float*)d_in[10];  // (2048, 1024)
    const float* write_b  = (const float*)d_in[11];
    const float* upd_gate = (const float*)d_in[12];
    const float* out_w    = (const float*)d_in[13];  // (2048, 512)
    const float* out_b    = (const float*)d_in[14];
    const float* cw1 = (const float*)d_in[15]; const float* cb1 = (const float*)d_in[16];
    const float* cw2 = (const float*)d_in[17]; const float* cb2 = (const float*)d_in[18];
    const float* cw3 = (const float*)d_in[19]; const float* cb3 = (const float*)d_in[20];
    const float* cw4 = (const float*)d_in[21]; const float* cb4 = (const float*)d_in[22];
    const float* cw5 = (const float*)d_in[23]; const float* cb5 = (const float*)d_in[24];
    const float* thr = (const float*)d_in[25];

    char* ws = (char*)d_ws;
    float* gate   = (float*)(ws + GATE_OFF);
    float* actw   = (float*)(ws + ACTW_OFF);
    float* uvec   = (float*)(ws + U_OFF);
    float* cmean  = (float*)(ws + CMEAN_OFF);
    bf16*  hidden = (bf16*)(ws + HIDDEN_OFF);
    bf16*  ratt   = (bf16*)(ws + RATT_OFF);
    bf16*  cand   = (bf16*)(ws + CAND_OFF);
    float* preds  = (float*)(ws + PREDS_OFF);
    float* readv  = (float*)(ws + READ_OFF);

    float* out0 = (float*)d_out;            // (1024, 512)
    float* out1 = out0 + 1024*512;          // (2048, 1024)

    k_gate<<<1024, 256, 0, stream>>>(x, gate_w, gate_b, act_w, gate, actw);

    // hidden = qact((x@w + b)·gate) * mask        [M=1024, N=8192, K=1024]
    gemm_nn<4, 1><<<dim3(64, 8), 256, 0, stream>>>(x, w_, 1024, 8192,
        b_bias, nullptr, hidden, gate, actw, mask, 2048);
    // att logits = hidden @ att_w + att_b         [M=1024, N=2048, K=2048]
    gemm_nn<0, 0><<<dim3(16, 8), 256, 0, stream>>>(hidden, att_w, 2048, 2048,
        att_b, nullptr, ratt, nullptr, nullptr, nullptr, 2048);
    k_softmax<<<1024, 256, 0, stream>>>(ratt);
    // cand = tanh(hidden @ write_w + write_b)     [M=1024, N=1024, K=2048]
    gemm_nn<1, 0><<<dim3(8, 8), 256, 0, stream>>>(hidden, write_w, 2048, 1024,
        write_b, nullptr, cand, nullptr, nullptr, nullptr, 1024);
    // preds = hidden @ out_w + out_b (f32)        [M=1024, N=512, K=2048]
    gemm_nn<2, 0><<<dim3(4, 8), 256, 0, stream>>>(hidden, out_w, 2048, 512,
        out_b, preds, nullptr, nullptr, nullptr, nullptr, 512);
    // read = ratt @ mem (f32)                     [M=1024, N=1024, K=2048]
    gemm_nn<3, 0><<<dim3(8, 8), 256, 0, stream>>>(ratt, mem, 2048, 1024,
        nullptr, readv, nullptr, nullptr, nullptr, nullptr, 1024);

    k_colmeans<<<12, 256, 0, stream>>>(ratt, cand, upd_gate, uvec, cmean);
    k_newmem<<<8192, 256, 0, stream>>>(mem, uvec, cmean, out1);
    k_critic<<<1024, 256, 0, stream>>>(readv, preds, hidden,
        cw1, cb1, cw2, cb2, cw3, cb3, cw4, cb4, cw5, cb5, thr, out0);
}